// Round 1
// baseline (827.048 us; speedup 1.0000x reference)
//
#include <hip/hip_runtime.h>
#include <stdint.h>

#define K_DIM 2048
#define N_DIM 2048
#define M_TOK 32768

typedef float v4f __attribute__((ext_vector_type(4)));
typedef short bf16x8 __attribute__((ext_vector_type(8)));
typedef unsigned short u16;

// ---------------- workspace layout (bytes) ----------------
// 0        : double wpart[1024]                 (8192 B)
// 8192     : float  wstat[2]  {winv, w_scale}
// 8448     : float  tscale[32768]               (131072 B, ends 139520)
// 262144   : u16    wt[2048*2048]   ternary bf16 (8388608 B, ends 8650752)
// 8650752  : u16    qx[32768*2048]  int-val bf16 (134217728 B, ends 142868480)
#define WS_PART   0
#define WS_STAT   8192
#define WS_TSCALE 8448
#define WS_WT     262144
#define WS_QX     8650752

// ---------------- helpers ----------------
__device__ __forceinline__ u16 f2bf(float f) {
    union { float f; unsigned int u; } v; v.f = f;
    unsigned int r = v.u + 0x7fffu + ((v.u >> 16) & 1u);  // RNE
    return (u16)(r >> 16);
}

__device__ __forceinline__ void gload_lds16(const void* g, void* l) {
    __builtin_amdgcn_global_load_lds(
        (const __attribute__((address_space(1))) unsigned int*)g,
        (__attribute__((address_space(3))) unsigned int*)l,
        16, 0, 0);
}

__device__ __forceinline__ float block_sum256(float v, float* red) {
    int lane = threadIdx.x & 63, wv = threadIdx.x >> 6;
#pragma unroll
    for (int off = 32; off > 0; off >>= 1) v += __shfl_down(v, off, 64);
    if (lane == 0) red[wv] = v;
    __syncthreads();
    return red[0] + red[1] + red[2] + red[3];
}

// ---------------- kernel 1: partial sum of |W| (double accum) ----------------
__global__ __launch_bounds__(256) void wabs_partial(const float* __restrict__ W,
                                                    double* __restrict__ part) {
    const int t = threadIdx.x, b = blockIdx.x;
    const float* p = W + (size_t)b * 4096;
    double s = 0.0;
#pragma unroll
    for (int i = 0; i < 4; ++i) {
        float4 v = *(const float4*)(p + i * 1024 + t * 4);
        s += (double)fabsf(v.x) + (double)fabsf(v.y) +
             (double)fabsf(v.z) + (double)fabsf(v.w);
    }
    int lane = t & 63, wv = t >> 6;
#pragma unroll
    for (int off = 32; off > 0; off >>= 1) s += __shfl_down(s, off, 64);
    __shared__ double red[4];
    if (lane == 0) red[wv] = s;
    __syncthreads();
    if (t == 0) part[b] = red[0] + red[1] + red[2] + red[3];
}

// ---------------- kernel 2: finalize w_scale ----------------
__global__ __launch_bounds__(256) void wfinal(const double* __restrict__ part,
                                              float* __restrict__ wstat) {
    const int t = threadIdx.x;
    double s = part[t] + part[t + 256] + part[t + 512] + part[t + 768];
    int lane = t & 63, wv = t >> 6;
#pragma unroll
    for (int off = 32; off > 0; off >>= 1) s += __shfl_down(s, off, 64);
    __shared__ double red[4];
    if (lane == 0) red[wv] = s;
    __syncthreads();
    if (t == 0) {
        double mean = (red[0] + red[1] + red[2] + red[3]) * (1.0 / 4194304.0);
        float winv = (float)mean + 1e-5f;        // = 1/w_scale
        wstat[0] = winv;
        wstat[1] = 1.0f / winv;                  // = w_scale
    }
}

// ---------------- kernel 3: quantize W -> ternary (stored as bf16) ----------------
__global__ __launch_bounds__(256) void wquant(const float* __restrict__ W,
                                              const float* __restrict__ wstat,
                                              u16* __restrict__ wt) {
    const float wsc = wstat[1];
    size_t i = ((size_t)blockIdx.x * 256 + threadIdx.x) * 4;
    float4 v = *(const float4*)(W + i);
    ushort4 o;
    o.x = f2bf(fminf(fmaxf(rintf(v.x * wsc), -1.0f), 1.0f));
    o.y = f2bf(fminf(fmaxf(rintf(v.y * wsc), -1.0f), 1.0f));
    o.z = f2bf(fminf(fmaxf(rintf(v.z * wsc), -1.0f), 1.0f));
    o.w = f2bf(fminf(fmaxf(rintf(v.w * wsc), -1.0f), 1.0f));
    *(ushort4*)(wt + i) = o;
}

// ---------------- kernel 4: RMSNorm + per-token absmax int8-value quant ----------------
__global__ __launch_bounds__(256) void rmsnorm_quant(const float* __restrict__ x,
                                                     const float* __restrict__ gamma,
                                                     const float* __restrict__ wstat,
                                                     u16* __restrict__ qx,
                                                     float* __restrict__ tscale) {
    const int row = blockIdx.x;
    const int t = threadIdx.x;
    const float* xr = x + (size_t)row * K_DIM;

    float4 v0 = *(const float4*)(xr + t * 4);
    float4 v1 = *(const float4*)(xr + 1024 + t * 4);
    float4 g0 = *(const float4*)(gamma + t * 4);
    float4 g1 = *(const float4*)(gamma + 1024 + t * 4);

    float ss = v0.x * v0.x + v0.y * v0.y + v0.z * v0.z + v0.w * v0.w +
               v1.x * v1.x + v1.y * v1.y + v1.z * v1.z + v1.w * v1.w;

    __shared__ float red[8];
    {
        int lane = t & 63, wv = t >> 6;
#pragma unroll
        for (int off = 32; off > 0; off >>= 1) ss += __shfl_down(ss, off, 64);
        if (lane == 0) red[wv] = ss;
        __syncthreads();
        ss = red[0] + red[1] + red[2] + red[3];
    }
    const float rms = 1.0f / sqrtf(ss * (1.0f / 2048.0f) + 1e-6f);

    float xn[8];
    xn[0] = v0.x * rms * g0.x;  xn[1] = v0.y * rms * g0.y;
    xn[2] = v0.z * rms * g0.z;  xn[3] = v0.w * rms * g0.w;
    xn[4] = v1.x * rms * g1.x;  xn[5] = v1.y * rms * g1.y;
    xn[6] = v1.z * rms * g1.z;  xn[7] = v1.w * rms * g1.w;

    float am = 0.0f;
#pragma unroll
    for (int j = 0; j < 8; ++j) am = fmaxf(am, fabsf(xn[j]));
    {
        int lane = t & 63, wv = t >> 6;
#pragma unroll
        for (int off = 32; off > 0; off >>= 1) am = fmaxf(am, __shfl_down(am, off, 64));
        if (lane == 0) red[4 + wv] = am;
        __syncthreads();
        am = fmaxf(fmaxf(red[4], red[5]), fmaxf(red[6], red[7]));
    }
    const float amp = am + 1e-5f;
    const float ascale = 127.0f / amp;

    u16 q[8];
#pragma unroll
    for (int j = 0; j < 8; ++j)
        q[j] = f2bf(fminf(fmaxf(rintf(xn[j] * ascale), -128.0f), 127.0f));

    ushort4 o0; o0.x = q[0]; o0.y = q[1]; o0.z = q[2]; o0.w = q[3];
    ushort4 o1; o1.x = q[4]; o1.y = q[5]; o1.z = q[6]; o1.w = q[7];
    u16* qr = qx + (size_t)row * K_DIM;
    *(ushort4*)(qr + t * 4) = o0;
    *(ushort4*)(qr + 1024 + t * 4) = o1;

    if (t == 0) tscale[row] = amp * wstat[0] * (1.0f / 127.0f);
}

// ---------------- kernel 5: bf16 MFMA GEMM, 128x128 tile, BK=64 ----------------
// C[m,n] = tscale[m] * sum_k qx[m,k] * wt[n,k]   (both operands K-major)
__global__ __launch_bounds__(256) void gemm_bt(const u16* __restrict__ qx,
                                               const u16* __restrict__ wt,
                                               const float* __restrict__ tscale,
                                               float* __restrict__ out) {
    __shared__ u16 lds_a[128 * 64];
    __shared__ u16 lds_b[128 * 64];

    const int t = threadIdx.x;
    const int lane = t & 63;
    const int wv = t >> 6;
    const int bn0 = blockIdx.x * 128;
    const int bm0 = blockIdx.y * 128;
    const int wm = (wv >> 1) * 64;   // wave row offset in tile
    const int wn = (wv & 1) * 64;    // wave col offset in tile
    const int quad = lane >> 4;
    const int l16 = lane & 15;

    v4f acc[4][4];
    const v4f vzero = {0.0f, 0.0f, 0.0f, 0.0f};
#pragma unroll
    for (int i = 0; i < 4; ++i)
#pragma unroll
        for (int j = 0; j < 4; ++j) acc[i][j] = vzero;

    // staging geometry (16B chunks, XOR swizzle within each 128B row)
    // lds chunk index c = cc*256 + t ; row = c>>3 ; jl = c&7 ; global col-chunk jg = jl ^ (row&7)
    int srow[4], sjg[4];
#pragma unroll
    for (int cc = 0; cc < 4; ++cc) {
        int c = cc * 256 + t;
        srow[cc] = c >> 3;
        sjg[cc] = (c & 7) ^ (srow[cc] & 7);
    }
    const size_t baseA = (size_t)bm0 * K_DIM;
    const size_t baseB = (size_t)bn0 * K_DIM;

    for (int k0 = 0; k0 < K_DIM; k0 += 64) {
        __syncthreads();
#pragma unroll
        for (int cc = 0; cc < 4; ++cc) {
            const u16* ga = qx + baseA + (size_t)srow[cc] * K_DIM + k0 + sjg[cc] * 8;
            const u16* gb = wt + baseB + (size_t)srow[cc] * K_DIM + k0 + sjg[cc] * 8;
            char* la = (char*)lds_a + (cc * 256 + wv * 64) * 16;  // wave-uniform base
            char* lb = (char*)lds_b + (cc * 256 + wv * 64) * 16;
            gload_lds16(ga, la);
            gload_lds16(gb, lb);
        }
        __syncthreads();

#pragma unroll
        for (int kh = 0; kh < 2; ++kh) {
            bf16x8 af[4], bfr[4];
            const int j = kh * 4 + quad;
#pragma unroll
            for (int ti = 0; ti < 4; ++ti) {
                const int ra = wm + ti * 16 + l16;
                af[ti] = *(const bf16x8*)((const char*)lds_a + ra * 128 + ((j ^ (ra & 7)) * 16));
                const int rb = wn + ti * 16 + l16;
                bfr[ti] = *(const bf16x8*)((const char*)lds_b + rb * 128 + ((j ^ (rb & 7)) * 16));
            }
#pragma unroll
            for (int ti = 0; ti < 4; ++ti)
#pragma unroll
                for (int tj = 0; tj < 4; ++tj)
                    acc[ti][tj] = __builtin_amdgcn_mfma_f32_16x16x32_bf16(
                        af[ti], bfr[tj], acc[ti][tj], 0, 0, 0);
        }
    }

    // epilogue: D layout col=lane&15, row=quad*4+r (m89/m91-verified)
#pragma unroll
    for (int ti = 0; ti < 4; ++ti) {
#pragma unroll
        for (int r = 0; r < 4; ++r) {
            const int row = bm0 + wm + ti * 16 + quad * 4 + r;
            const float s = tscale[row];
            float* op = out + (size_t)row * N_DIM + bn0 + wn + l16;
#pragma unroll
            for (int tj = 0; tj < 4; ++tj)
                op[tj * 16] = acc[ti][tj][r] * s;
        }
    }
}

// ---------------- launch ----------------
extern "C" void kernel_launch(void* const* d_in, const int* in_sizes, int n_in,
                              void* d_out, int out_size, void* d_ws, size_t ws_size,
                              hipStream_t stream) {
    const float* x     = (const float*)d_in[0];
    const float* gamma = (const float*)d_in[1];
    const float* W     = (const float*)d_in[2];
    float* out = (float*)d_out;

    char* ws = (char*)d_ws;
    double* wpart  = (double*)(ws + WS_PART);
    float*  wstat  = (float*)(ws + WS_STAT);
    float*  tscale = (float*)(ws + WS_TSCALE);
    u16*    wt     = (u16*)(ws + WS_WT);
    u16*    qx     = (u16*)(ws + WS_QX);

    wabs_partial<<<1024, 256, 0, stream>>>(W, wpart);
    wfinal<<<1, 256, 0, stream>>>(wpart, wstat);
    wquant<<<4096, 256, 0, stream>>>(W, wstat, wt);
    rmsnorm_quant<<<M_TOK, 256, 0, stream>>>(x, gamma, wstat, qx, tscale);

    dim3 grid(N_DIM / 128, M_TOK / 128);
    gemm_bt<<<grid, 256, 0, stream>>>(qx, wt, tscale, out);
}

// Round 2
// 645.436 us; speedup vs baseline: 1.2814x; 1.2814x over previous
//
#include <hip/hip_runtime.h>
#include <stdint.h>

#define K_DIM 2048
#define N_DIM 2048
#define M_TOK 32768

typedef float v4f __attribute__((ext_vector_type(4)));
typedef int   v4i __attribute__((ext_vector_type(4)));

// ---------------- workspace layout (bytes) ----------------
// 0        : double wpart[1024]                  (8192 B)
// 8192     : float  wstat[2]  {winv, w_scale}
// 8448     : float  tscale[32768]                (131072 B, ends 139520)
// 262144   : int8   wt[2048*2048]   ternary      (4 MB, ends 4456448)
// 4456448  : int8   qx[32768*2048]  int8 values  (67 MB, ends 71565312)
#define WS_PART   0
#define WS_STAT   8192
#define WS_TSCALE 8448
#define WS_WT     262144
#define WS_QX     4456448

// ---------------- helpers ----------------
__device__ __forceinline__ void gload_lds16(const void* g, void* l) {
    __builtin_amdgcn_global_load_lds(
        (const __attribute__((address_space(1))) unsigned int*)g,
        (__attribute__((address_space(3))) unsigned int*)l,
        16, 0, 0);
}

__device__ __forceinline__ unsigned int pack4(int a, int b, int c, int d) {
    return (unsigned int)(a & 255) | ((unsigned int)(b & 255) << 8) |
           ((unsigned int)(c & 255) << 16) | ((unsigned int)(d & 255) << 24);
}

// ---------------- kernel 1: partial sum of |W| (double accum) ----------------
__global__ __launch_bounds__(256) void wabs_partial(const float* __restrict__ W,
                                                    double* __restrict__ part) {
    const int t = threadIdx.x, b = blockIdx.x;
    const float* p = W + (size_t)b * 4096;
    double s = 0.0;
#pragma unroll
    for (int i = 0; i < 4; ++i) {
        float4 v = *(const float4*)(p + i * 1024 + t * 4);
        s += (double)fabsf(v.x) + (double)fabsf(v.y) +
             (double)fabsf(v.z) + (double)fabsf(v.w);
    }
    int lane = t & 63, wv = t >> 6;
#pragma unroll
    for (int off = 32; off > 0; off >>= 1) s += __shfl_down(s, off, 64);
    __shared__ double red[4];
    if (lane == 0) red[wv] = s;
    __syncthreads();
    if (t == 0) part[b] = red[0] + red[1] + red[2] + red[3];
}

// ---------------- kernel 2: finalize w_scale ----------------
__global__ __launch_bounds__(256) void wfinal(const double* __restrict__ part,
                                              float* __restrict__ wstat) {
    const int t = threadIdx.x;
    double s = part[t] + part[t + 256] + part[t + 512] + part[t + 768];
    int lane = t & 63, wv = t >> 6;
#pragma unroll
    for (int off = 32; off > 0; off >>= 1) s += __shfl_down(s, off, 64);
    __shared__ double red[4];
    if (lane == 0) red[wv] = s;
    __syncthreads();
    if (t == 0) {
        double mean = (red[0] + red[1] + red[2] + red[3]) * (1.0 / 4194304.0);
        float winv = (float)mean + 1e-5f;        // = 1/w_scale
        wstat[0] = winv;
        wstat[1] = 1.0f / winv;                  // = w_scale
    }
}

// ---------------- kernel 3: quantize W -> ternary int8 ----------------
__global__ __launch_bounds__(256) void wquant(const float* __restrict__ W,
                                              const float* __restrict__ wstat,
                                              int8_t* __restrict__ wt) {
    const float wsc = wstat[1];
    size_t i = ((size_t)blockIdx.x * 256 + threadIdx.x) * 4;
    float4 v = *(const float4*)(W + i);
    int q0 = (int)rintf(fminf(fmaxf(v.x * wsc, -1.0f), 1.0f));
    int q1 = (int)rintf(fminf(fmaxf(v.y * wsc, -1.0f), 1.0f));
    int q2 = (int)rintf(fminf(fmaxf(v.z * wsc, -1.0f), 1.0f));
    int q3 = (int)rintf(fminf(fmaxf(v.w * wsc, -1.0f), 1.0f));
    *(unsigned int*)(wt + i) = pack4(q0, q1, q2, q3);
}

// ---------------- kernel 4: RMSNorm + per-token absmax int8 quant ----------------
__global__ __launch_bounds__(256) void rmsnorm_quant(const float* __restrict__ x,
                                                     const float* __restrict__ gamma,
                                                     const float* __restrict__ wstat,
                                                     int8_t* __restrict__ qx,
                                                     float* __restrict__ tscale) {
    const int row = blockIdx.x;
    const int t = threadIdx.x;
    const float* xr = x + (size_t)row * K_DIM;

    float4 v0 = *(const float4*)(xr + t * 4);
    float4 v1 = *(const float4*)(xr + 1024 + t * 4);
    float4 g0 = *(const float4*)(gamma + t * 4);
    float4 g1 = *(const float4*)(gamma + 1024 + t * 4);

    float ss = v0.x * v0.x + v0.y * v0.y + v0.z * v0.z + v0.w * v0.w +
               v1.x * v1.x + v1.y * v1.y + v1.z * v1.z + v1.w * v1.w;

    __shared__ float red[8];
    {
        int lane = t & 63, wv = t >> 6;
#pragma unroll
        for (int off = 32; off > 0; off >>= 1) ss += __shfl_down(ss, off, 64);
        if (lane == 0) red[wv] = ss;
        __syncthreads();
        ss = red[0] + red[1] + red[2] + red[3];
    }
    const float rms = 1.0f / sqrtf(ss * (1.0f / 2048.0f) + 1e-6f);

    float xn[8];
    xn[0] = v0.x * rms * g0.x;  xn[1] = v0.y * rms * g0.y;
    xn[2] = v0.z * rms * g0.z;  xn[3] = v0.w * rms * g0.w;
    xn[4] = v1.x * rms * g1.x;  xn[5] = v1.y * rms * g1.y;
    xn[6] = v1.z * rms * g1.z;  xn[7] = v1.w * rms * g1.w;

    float am = 0.0f;
#pragma unroll
    for (int j = 0; j < 8; ++j) am = fmaxf(am, fabsf(xn[j]));
    {
        int lane = t & 63, wv = t >> 6;
#pragma unroll
        for (int off = 32; off > 0; off >>= 1) am = fmaxf(am, __shfl_down(am, off, 64));
        if (lane == 0) red[4 + wv] = am;
        __syncthreads();
        am = fmaxf(fmaxf(red[4], red[5]), fmaxf(red[6], red[7]));
    }
    const float amp = am + 1e-5f;
    const float ascale = 127.0f / amp;

    int q[8];
#pragma unroll
    for (int j = 0; j < 8; ++j)
        q[j] = (int)rintf(fminf(fmaxf(xn[j] * ascale, -128.0f), 127.0f));

    int8_t* qr = qx + (size_t)row * K_DIM;
    *(unsigned int*)(qr + t * 4)        = pack4(q[0], q[1], q[2], q[3]);
    *(unsigned int*)(qr + 1024 + t * 4) = pack4(q[4], q[5], q[6], q[7]);

    if (t == 0) tscale[row] = amp * wstat[0] * (1.0f / 127.0f);
}

// ---------------- kernel 5: i8 MFMA GEMM, 128x128 tile, BK=128 bytes ----------------
// C[m,n] = tscale[m] * sum_k qx[m,k] * wt[n,k]   (both operands K-major, int8)
__global__ __launch_bounds__(256) void gemm_i8(const int8_t* __restrict__ qx,
                                               const int8_t* __restrict__ wt,
                                               const float* __restrict__ tscale,
                                               float* __restrict__ out) {
    __shared__ int8_t lds_a[128 * 128];
    __shared__ int8_t lds_b[128 * 128];

    const int t = threadIdx.x;
    const int lane = t & 63;
    const int wv = t >> 6;
    const int bn0 = blockIdx.x * 128;
    const int bm0 = blockIdx.y * 128;
    const int wm = (wv >> 1) * 64;
    const int wn = (wv & 1) * 64;
    const int quad = lane >> 4;
    const int l16 = lane & 15;

    v4i acc[4][4];
    const v4i izero = {0, 0, 0, 0};
#pragma unroll
    for (int i = 0; i < 4; ++i)
#pragma unroll
        for (int j = 0; j < 4; ++j) acc[i][j] = izero;

    // staging: 16B chunks; chunk c = cc*256 + t; row = c>>3; jg = (c&7)^(row&7)
    int srow[4], sjg[4];
#pragma unroll
    for (int cc = 0; cc < 4; ++cc) {
        int c = cc * 256 + t;
        srow[cc] = c >> 3;
        sjg[cc] = (c & 7) ^ (srow[cc] & 7);
    }
    const size_t baseA = (size_t)bm0 * K_DIM;
    const size_t baseB = (size_t)bn0 * K_DIM;

    for (int k0 = 0; k0 < K_DIM; k0 += 128) {
        __syncthreads();
#pragma unroll
        for (int cc = 0; cc < 4; ++cc) {
            const int8_t* ga = qx + baseA + (size_t)srow[cc] * K_DIM + k0 + sjg[cc] * 16;
            const int8_t* gb = wt + baseB + (size_t)srow[cc] * K_DIM + k0 + sjg[cc] * 16;
            int8_t* la = lds_a + (cc * 256 + wv * 64) * 16;  // wave-uniform base
            int8_t* lb = lds_b + (cc * 256 + wv * 64) * 16;
            gload_lds16(ga, la);
            gload_lds16(gb, lb);
        }
        __syncthreads();

#pragma unroll
        for (int kh = 0; kh < 2; ++kh) {
            v4i af[4], bfr[4];
            const int j = kh * 4 + quad;   // 16B chunk index within the 128B row
#pragma unroll
            for (int ti = 0; ti < 4; ++ti) {
                const int ra = wm + ti * 16 + l16;
                af[ti] = *(const v4i*)(lds_a + ra * 128 + ((j ^ (ra & 7)) * 16));
                const int rb = wn + ti * 16 + l16;
                bfr[ti] = *(const v4i*)(lds_b + rb * 128 + ((j ^ (rb & 7)) * 16));
            }
#pragma unroll
            for (int ti = 0; ti < 4; ++ti)
#pragma unroll
                for (int tj = 0; tj < 4; ++tj)
                    acc[ti][tj] = __builtin_amdgcn_mfma_i32_16x16x64_i8(
                        af[ti], bfr[tj], acc[ti][tj], 0, 0, 0);
        }
    }

    // epilogue: D layout col=lane&15, row=quad*4+r (dtype-independent, m121-128)
#pragma unroll
    for (int ti = 0; ti < 4; ++ti) {
#pragma unroll
        for (int r = 0; r < 4; ++r) {
            const int row = bm0 + wm + ti * 16 + quad * 4 + r;
            const float s = tscale[row];
            float* op = out + (size_t)row * N_DIM + bn0 + wn + l16;
#pragma unroll
            for (int tj = 0; tj < 4; ++tj)
                op[tj * 16] = (float)acc[ti][tj][r] * s;
        }
    }
}

// ---------------- launch ----------------
extern "C" void kernel_launch(void* const* d_in, const int* in_sizes, int n_in,
                              void* d_out, int out_size, void* d_ws, size_t ws_size,
                              hipStream_t stream) {
    const float* x     = (const float*)d_in[0];
    const float* gamma = (const float*)d_in[1];
    const float* W     = (const float*)d_in[2];
    float* out = (float*)d_out;

    char* ws = (char*)d_ws;
    double* wpart  = (double*)(ws + WS_PART);
    float*  wstat  = (float*)(ws + WS_STAT);
    float*  tscale = (float*)(ws + WS_TSCALE);
    int8_t* wt     = (int8_t*)(ws + WS_WT);
    int8_t* qx     = (int8_t*)(ws + WS_QX);

    wabs_partial<<<1024, 256, 0, stream>>>(W, wpart);
    wfinal<<<1, 256, 0, stream>>>(wpart, wstat);
    wquant<<<4096, 256, 0, stream>>>(W, wstat, wt);
    rmsnorm_quant<<<M_TOK, 256, 0, stream>>>(x, gamma, wstat, qx, tscale);

    dim3 grid(N_DIM / 128, M_TOK / 128);
    gemm_i8<<<grid, 256, 0, stream>>>(qx, wt, tscale, out);
}